// Round 8
// baseline (440.406 us; speedup 1.0000x reference)
//
#include <hip/hip_runtime.h>

// Problem constants (fixed by setup_inputs)
#define S_LEN   2048
#define D_DIM   128
#define KH_N    4
#define QH_N    4
#define H_N     (KH_N * QH_N)
#define SINK_N  16
#define MAXW    160    // >= window(128) + sink(16)
#define MAXC    1904   // >= S - SINK - window
#define MAXT    2048   // unified list capacity (s+1 <= 2048)
#define NREG    32     // ceil(2048/64) unified scores per lane
#define CHUNK   512    // rows scored per LDS chunk
#define MAXSEL  208    // window(144) + top_k(64)
#define PLANE   676    // floats per buf plane (676 % 32 == 4 -> bank-skewed;
                       // holds 512 chunk scores, later 256-u32 hist + 208 u64 sel)

typedef __attribute__((ext_vector_type(8))) short bf16x8;
typedef __attribute__((ext_vector_type(4))) float f32x4;
typedef __attribute__((ext_vector_type(2))) float f32x2;

__device__ __forceinline__ void lds_fence() {
  asm volatile("s_waitcnt lgkmcnt(0)" ::: "memory");
}
__device__ __forceinline__ unsigned int okey(float f) {
  unsigned int b = __float_as_uint(f);
  return (b & 0x80000000u) ? ~b : (b | 0x80000000u);
}
__device__ __forceinline__ float okinv(unsigned int u) {  // inverse of okey
  return __uint_as_float((u & 0x80000000u) ? (u & 0x7fffffffu) : ~u);
}
__device__ __forceinline__ unsigned short f2bf(float f) {  // RNE
  unsigned int u = __float_as_uint(f);
  u += 0x7FFFu + ((u >> 16) & 1u);
  return (unsigned short)(u >> 16);
}
__device__ __forceinline__ float bf2f(unsigned short h) {
  return __uint_as_float(((unsigned int)h) << 16);
}

// ---------------------------------------------------------------------------
// Kernel 1 (k/v only): one wave per 4 rows, row-type uniform per wave.
// [0,8192) k rows: sign words + bf16 hi/lo planes. [8192,16384) v rows:
// packed bf16 plane.
// ---------------------------------------------------------------------------
__global__ __launch_bounds__(256) void pack_kernel(
    const float* __restrict__ k, const float* __restrict__ v,
    unsigned long long* __restrict__ signs,
    unsigned short* __restrict__ kbf, unsigned int* __restrict__ vbf) {
  const int wid  = (blockIdx.x * 256 + threadIdx.x) >> 6;
  const int lane = threadIdx.x & 63;
  const int rbase = wid * 4;
  const int KROWS = KH_N * S_LEN;           // 8192

  if (rbase < KROWS) {
    const float* src = k + (size_t)rbase * D_DIM;
    float a[4], b[4];
#pragma unroll
    for (int r = 0; r < 4; r++) {
      a[r] = src[r * D_DIM + lane];
      b[r] = src[r * D_DIM + 64 + lane];
    }
#pragma unroll
    for (int r = 0; r < 4; r++) {
      unsigned long long b0 = __ballot(a[r] >= 0.0f);
      unsigned long long b1 = __ballot(b[r] >= 0.0f);
      if (lane == 0) {
        signs[(size_t)(rbase + r) * 2]     = b0;
        signs[(size_t)(rbase + r) * 2 + 1] = b1;
      }
      unsigned short h0 = f2bf(a[r]), h1 = f2bf(b[r]);
      unsigned short l0 = f2bf(a[r] - bf2f(h0)), l1 = f2bf(b[r] - bf2f(h1));
      unsigned short* rb = kbf + (size_t)(rbase + r) * 256;  // 128 hi | 128 lo
      rb[lane]       = h0;  rb[64 + lane]  = h1;
      rb[128 + lane] = l0;  rb[192 + lane] = l1;
    }
  } else {
    int vr = rbase - KROWS;
    const float* src = v + (size_t)vr * D_DIM;
    float2 f2[4];
#pragma unroll
    for (int r = 0; r < 4; r++)
      f2[r] = *(const float2*)(src + r * D_DIM + lane * 2);
#pragma unroll
    for (int r = 0; r < 4; r++) {
      unsigned int pk = (unsigned int)f2bf(f2[r].x) |
                        ((unsigned int)f2bf(f2[r].y) << 16);
      vbf[(size_t)(vr + r) * 64 + lane] = pk;
    }
  }
}

// ---------------------------------------------------------------------------
// Kernel 2: one block (4 waves) per (kh, s); wave == qh within the GQA group.
// blockIdx swizzle: xcd = blockIdx&7 (typical round-robin block->XCD), each
// kh owned by 2 XCDs -> per-XCD L2 working set ~1.5 MB (kbf+vbf slice).
// __launch_bounds__(256,4): 128-reg combined budget (creg stays in AGPRs;
// (256,8) spilled 344 MB to scratch in round 6).
// ---------------------------------------------------------------------------
__global__ __launch_bounds__(256, 4) void attn_kernel(
    const float* __restrict__ query, const float* __restrict__ thr,
    const int* __restrict__ p_topk, const int* __restrict__ p_wsz,
    const unsigned long long* __restrict__ signs,
    const unsigned short* __restrict__ kbf,
    const unsigned int* __restrict__ vbf,
    float* __restrict__ out) {
  const int xcd  = blockIdx.x & 7;
  const int kh   = xcd >> 1;
  const int s    = (S_LEN - 1) - (((blockIdx.x >> 3) << 1) | (xcd & 1));
  const int tid  = threadIdx.x;
  const int lane = tid & 63;
  const int qh   = tid >> 6;
  const int col  = lane & 15;
  const int quad = lane >> 4;

  __shared__ __align__(16) float buf[QH_N * PLANE];        // 10816 B
  __shared__ __align__(16) unsigned short q_bf[8][136];    // 2176 B
  __shared__ unsigned short idx_sh[MAXT];                  // 4096 B
  __shared__ unsigned long long qs_sh[QH_N][2];
  __shared__ int ncand_sh;
  __shared__ int nsel_sh[QH_N];

  const int   topk   = *p_topk;   // 64
  const int   wsz    = *p_wsz;    // 128
  const float thresh = thr[kh];   // 70.0
  const float scale  = 0.088388347648318447f;  // 1/sqrt(128)

  // ---- load q rows; build q_bf (hi rows 0-3, lo rows 4-7) + q sign words ---
  {
    int h0 = tid >> 7, d = tid & 127;
    float f0 = query[((size_t)(kh * QH_N + h0) * S_LEN + s) * D_DIM + d];
    float f1 = query[((size_t)(kh * QH_N + h0 + 2) * S_LEN + s) * D_DIM + d];
    unsigned long long b0 = __ballot(f0 >= 0.0f);
    unsigned long long b1 = __ballot(f1 >= 0.0f);
    if (lane == 0) {
      qs_sh[qh >> 1][qh & 1] = b0;
      qs_sh[2 + (qh >> 1)][qh & 1] = b1;
    }
    f0 *= scale; f1 *= scale;
    unsigned short hi0 = f2bf(f0), hi1 = f2bf(f1);
    q_bf[h0][d]     = hi0;  q_bf[4 + h0][d]     = f2bf(f0 - bf2f(hi0));
    q_bf[h0 + 2][d] = hi1;  q_bf[4 + h0 + 2][d] = f2bf(f1 - bf2f(hi1));
  }
  if (tid == 0) ncand_sh = 0;

  // ---- window part of the unified list ----
  int wlo = s - (wsz - 1); if (wlo < 0) wlo = 0;
  int nsink = wlo < SINK_N ? wlo : SINK_N;
  int nw = nsink + (s - wlo + 1);
  if (nw > MAXW) nw = MAXW;
  for (int e = tid; e < nw; e += 256)
    idx_sh[e] = (unsigned short)(e < nsink ? e : wlo + (e - nsink));
  __syncthreads();

  // ---- Stage 1: LSH scan over [SINK, s-wsz] -> append candidates at nw ----
  unsigned long long qs0[QH_N], qs1[QH_N];
#pragma unroll
  for (int h = 0; h < QH_N; h++) { qs0[h] = qs_sh[h][0]; qs1[h] = qs_sh[h][1]; }
  const unsigned long long* ksg = signs + (size_t)kh * S_LEN * 2;
  int lt_hi = s - wsz;  // inclusive
  for (int l0 = SINK_N; l0 <= lt_hi; l0 += 256) {
    int l = l0 + tid;
    bool match = false;
    if (l <= lt_hi) {
      ulonglong2 kk = *(const ulonglong2*)(ksg + 2 * l);
      int best = 0;
#pragma unroll
      for (int h = 0; h < QH_N; h++) {
        int m = 128 - __popcll(qs0[h] ^ kk.x) - __popcll(qs1[h] ^ kk.y);
        best = best > m ? best : m;
      }
      match = ((float)best > thresh);
    }
    unsigned long long m = __ballot(match);
    if (m) {
      int base = 0;
      if (lane == 0) base = atomicAdd(&ncand_sh, __popcll(m));
      base = __shfl(base, 0);
      if (match) {
        int pos = base + __popcll(m & ((1ull << lane) - 1ull));
        if (pos < MAXC) idx_sh[nw + pos] = (unsigned short)l;
      }
    }
  }
  __syncthreads();
  int nc = ncand_sh < MAXC ? ncand_sh : MAXC;
  int ntot = nw + nc;
  int ntot_pad = (ntot + 15) & ~15;
  for (int i = ntot + tid; i < ntot_pad; i += 256) idx_sh[i] = 0;
  __syncthreads();

  // ---- Stage 2: MFMA scoring (hi/lo bf16 split), 1-deep prefetched ----
  bf16x8 bfrag[4];
  bf16x8 bzero = {0, 0, 0, 0, 0, 0, 0, 0};
#pragma unroll
  for (int ks = 0; ks < 4; ks++)
    bfrag[ks] = (col < 8) ? *(const bf16x8*)&q_bf[col][ks * 32 + quad * 8] : bzero;

  const unsigned short* kbf_h = kbf + ((size_t)kh << 11) * 256;
  unsigned int creg[NREG];     // ordered-uint score keys (AGPR-resident)
#pragma unroll
  for (int i = 0; i < NREG; i++) creg[i] = 0u;

  for (int cb = 0; cb < 4; cb++) {
    int cbase = cb * CHUNK;
    int chunk_n = ntot_pad - cbase;
    if (chunk_n <= 0) break;
    if (chunk_n > CHUNK) chunk_n = CHUNK;
    int ntiles = chunk_n >> 4;
    int t = qh;
    if (t < ntiles) {
      bf16x8 fa[8];
      {
        const unsigned char* ab = (const unsigned char*)
            (kbf_h + (size_t)idx_sh[cbase + t * 16 + col] * 256) + quad * 16;
#pragma unroll
        for (int i = 0; i < 8; i++) fa[i] = *(const bf16x8*)(ab + i * 64);
      }
      while (true) {
        int tn = t + QH_N;
        bool more = (tn < ntiles);
        bf16x8 fb[8];
        if (more) {
          const unsigned char* ab = (const unsigned char*)
              (kbf_h + (size_t)idx_sh[cbase + tn * 16 + col] * 256) + quad * 16;
#pragma unroll
          for (int i = 0; i < 8; i++) fb[i] = *(const bf16x8*)(ab + i * 64);
        }
        f32x4 acc = {0.f, 0.f, 0.f, 0.f};
        acc = __builtin_amdgcn_mfma_f32_16x16x32_bf16(fa[0], bfrag[0], acc, 0, 0, 0);
        acc = __builtin_amdgcn_mfma_f32_16x16x32_bf16(fa[4], bfrag[0], acc, 0, 0, 0);
        acc = __builtin_amdgcn_mfma_f32_16x16x32_bf16(fa[1], bfrag[1], acc, 0, 0, 0);
        acc = __builtin_amdgcn_mfma_f32_16x16x32_bf16(fa[5], bfrag[1], acc, 0, 0, 0);
        acc = __builtin_amdgcn_mfma_f32_16x16x32_bf16(fa[2], bfrag[2], acc, 0, 0, 0);
        acc = __builtin_amdgcn_mfma_f32_16x16x32_bf16(fa[6], bfrag[2], acc, 0, 0, 0);
        acc = __builtin_amdgcn_mfma_f32_16x16x32_bf16(fa[3], bfrag[3], acc, 0, 0, 0);
        acc = __builtin_amdgcn_mfma_f32_16x16x32_bf16(fa[7], bfrag[3], acc, 0, 0, 0);
        f32x4 t4;
#pragma unroll
        for (int r = 0; r < 4; r++) t4[r] = acc[r] + __shfl_xor(acc[r], 4);
        if (col < 4)
          *(f32x4*)&buf[col * PLANE + (t * 16 - 0) + quad * 4] = t4;
        if (!more) break;
#pragma unroll
        for (int i = 0; i < 8; i++) fa[i] = fb[i];
        t = tn;
      }
    }
    __syncthreads();
#pragma unroll
    for (int j = 0; j < 8; j++) {
      int v = j * 64 + lane;
      if (v < chunk_n) creg[cb * 8 + j] = okey(buf[qh * PLANE + v]);
    }
    __syncthreads();
  }
  const int imax = (ntot + 63) >> 6;

  // per-wave scratch carved from this wave's plane (chunk buffer is dead now)
  unsigned int*       histw = (unsigned int*)&buf[qh * PLANE];           // 256 u32
  unsigned long long* selq  = (unsigned long long*)&buf[qh * PLANE + 256]; // 208 u64

  // ---- cheap exact max: max over ALL scores == max over included set ----
  unsigned int mxu = 0;
#pragma unroll
  for (int i = 0; i < NREG; i++) {
    if (i >= imax) break;
    int e = lane + i * 64;
    if (e < ntot && creg[i] > mxu) mxu = creg[i];
  }
#pragma unroll
  for (int off = 32; off > 0; off >>= 1) {
    unsigned int t = __shfl_down(mxu, off);
    mxu = t > mxu ? t : mxu;
  }
  mxu = __shfl(mxu, 0);
  const float mxf = okinv(mxu);

  // ---- Stage 3: per-wave exact top-k threshold (radix-256, 4 passes) ----
  bool selAll = (nc <= topk);
  unsigned int tkey = 0;
  bool useTie = false;
  int l_cut = S_LEN;
  if (!selAll) {
    unsigned int prefix = 0;
    int want = topk;
    for (int pass = 0; pass < 4; pass++) {
      int sh = 24 - pass * 8;
#pragma unroll
      for (int j = 0; j < 4; j++) histw[lane * 4 + j] = 0;
      lds_fence();
#pragma unroll
      for (int i = 0; i < NREG; i++) {
        if (i >= imax) break;
        int e = lane + i * 64;
        if (e >= nw && e < ntot) {
          unsigned int u = creg[i];
          bool match = (pass == 0) || ((u >> (sh + 8)) == prefix);
          if (match) atomicAdd(&histw[(u >> sh) & 255u], 1u);
        }
      }
      lds_fence();
      unsigned int c0 = histw[lane * 4 + 0];
      unsigned int c1 = histw[lane * 4 + 1];
      unsigned int c2 = histw[lane * 4 + 2];
      unsigned int c3 = histw[lane * 4 + 3];
      unsigned int S3 = c3, S2 = c2 + S3, S1 = c1 + S2, S0 = c0 + S1;
      unsigned int tot = S0;
      unsigned int suf = tot;
#pragma unroll
      for (int off = 1; off < 64; off <<= 1) {
        unsigned int t = __shfl_down(suf, off);
        if (lane + off < 64) suf += t;
      }
      unsigned long long mk = __ballot(suf >= (unsigned int)want);
      int L = 63 - __clzll(mk);
      unsigned int se = suf - tot;
      unsigned int s3 = S3 + se, s2 = S2 + se, s1 = S1 + se, s0 = S0 + se;
      int j; unsigned int above;
      unsigned int w = (unsigned int)want;
      if (s3 >= w)      { j = 3; above = s3 - c3; }
      else if (s2 >= w) { j = 2; above = s2 - c2; }
      else if (s1 >= w) { j = 1; above = s1 - c1; }
      else              { j = 0; above = s0 - c0; }
      int d_me = (lane << 2) | j;
      int wp_me = want - (int)above;
      int digit = __shfl(d_me, L);
      want = __shfl(wp_me, L);
      prefix = (prefix << 8) | (unsigned int)digit;
    }
    tkey = prefix;
    // exact tie handling (lowest l wins, matching lax.top_k)
    int cgt = 0, ceq = 0;
#pragma unroll
    for (int i = 0; i < NREG; i++) {
      if (i >= imax) break;
      int e = lane + i * 64;
      if (e >= nw && e < ntot) {
        cgt += (creg[i] > tkey);
        ceq += (creg[i] == tkey);
      }
    }
#pragma unroll
    for (int off = 32; off > 0; off >>= 1) {
      cgt += __shfl_down(cgt, off);
      ceq += __shfl_down(ceq, off);
    }
    cgt = __shfl(cgt, 0); ceq = __shfl(ceq, 0);
    int rem = topk - cgt;
    if (ceq > rem) {
      useTie = true;
      int lo = 0, hi = S_LEN - 1;
      while (lo < hi) {
        int mid = (lo + hi) >> 1;
        int cn = 0;
#pragma unroll
        for (int i = 0; i < NREG; i++) {
          if (i >= imax) break;
          int e = lane + i * 64;
          if (e >= nw && e < ntot)
            cn += (creg[i] == tkey && (int)idx_sh[e] <= mid);
        }
#pragma unroll
        for (int off = 32; off > 0; off >>= 1) cn += __shfl_down(cn, off);
        cn = __shfl(cn, 0);
        if (cn >= rem) hi = mid; else lo = mid + 1;
      }
      l_cut = lo;
    }
  }

  // ---- Stage 4: fused select + exp + ballot-compact (single pass) ----
  if (lane == 0) nsel_sh[qh] = 0;
  lds_fence();
  float sum = 0.0f;
#pragma unroll
  for (int i = 0; i < NREG; i++) {
    if (i >= imax) break;
    int e = lane + i * 64;
    bool act = false;
    float p = 0.f;
    if (e < ntot) {
      unsigned int u = creg[i];
      bool inc = (e < nw) || selAll;
      if (!inc)
        inc = (u > tkey) || (u == tkey && (!useTie || (int)idx_sh[e] <= l_cut));
      if (inc) { act = true; p = __expf(okinv(u) - mxf); sum += p; }
    }
    unsigned long long m = __ballot(act);
    if (m) {
      int base = 0;
      if (lane == 0) base = atomicAdd(&nsel_sh[qh], __popcll(m));
      base = __shfl(base, 0);
      if (act) {
        int pi = base + __popcll(m & ((1ull << lane) - 1ull));
        selq[pi] = ((unsigned long long)idx_sh[e] << 32) |
                   (unsigned long long)__float_as_uint(p);
      }
    }
  }
#pragma unroll
  for (int off = 32; off > 0; off >>= 1) sum += __shfl_down(sum, off);
  sum = __shfl(sum, 0);
  float rinv = 1.0f / sum;

  lds_fence();
  int nsel = nsel_sh[qh];
  int nsel8 = (nsel + 7) & ~7;
  if (lane < nsel8 - nsel) selq[nsel + lane] = 0ull;  // pad: p=0, idx=0
  lds_fence();

  // ---- Stage 5: PV accumulate over bf16 V, 8-way unrolled ----
  float accx = 0.f, accy = 0.f;
  const unsigned int* vb = vbf + ((size_t)kh << 11) * 64 + lane;
  for (int e = 0; e < nsel8; e += 8) {
    unsigned long long q8[8];
#pragma unroll
    for (int j = 0; j < 8; j++) q8[j] = selq[e + j];
    unsigned int dv[8]; float pv[8];
#pragma unroll
    for (int j = 0; j < 8; j++) {
      pv[j] = __uint_as_float((unsigned int)q8[j]);
      dv[j] = vb[(size_t)(q8[j] >> 32) * 64];
    }
#pragma unroll
    for (int j = 0; j < 8; j++) {
      accx += pv[j] * __uint_as_float(dv[j] << 16);
      accy += pv[j] * __uint_as_float(dv[j] & 0xFFFF0000u);
    }
  }
  size_t o = (size_t)s * (H_N * D_DIM) + (size_t)(kh * QH_N + qh) * D_DIM + lane * 2;
  f32x2 res = {accx * rinv, accy * rinv};
  __builtin_nontemporal_store(res, (f32x2*)(out + o));
}

// ---------------------------------------------------------------------------
extern "C" void kernel_launch(void* const* d_in, const int* in_sizes, int n_in,
                              void* d_out, int out_size, void* d_ws, size_t ws_size,
                              hipStream_t stream) {
  const float* query = (const float*)d_in[0];
  const float* key   = (const float*)d_in[1];
  const float* value = (const float*)d_in[2];
  const float* thr   = (const float*)d_in[3];
  const int* p_topk  = (const int*)d_in[4];
  const int* p_wsz   = (const int*)d_in[5];
  float* out = (float*)d_out;

  // ws layout: k-signs 8192*16B = 128 KB | kbf 8192*512B = 4 MB | vbf 8192*256B = 2 MB
  char* ws = (char*)d_ws;
  unsigned long long* signs = (unsigned long long*)ws;
  unsigned short* kbf = (unsigned short*)(ws + (size_t)KH_N * S_LEN * 16);
  unsigned int* vbf = (unsigned int*)(ws + (size_t)KH_N * S_LEN * 16
                                         + (size_t)KH_N * S_LEN * 512);

  // 16384 k+v rows, 4 rows/wave, 4 waves/block -> 1024 blocks
  pack_kernel<<<1024, 256, 0, stream>>>(key, value, signs, kbf, vbf);

  attn_kernel<<<KH_N * S_LEN, 256, 0, stream>>>(
      query, thr, p_topk, p_wsz, signs, kbf, vbf, out);
}

// Round 9
// 400.568 us; speedup vs baseline: 1.0995x; 1.0995x over previous
//
#include <hip/hip_runtime.h>

// Problem constants (fixed by setup_inputs)
#define S_LEN   2048
#define D_DIM   128
#define KH_N    4
#define QH_N    4
#define H_N     (KH_N * QH_N)
#define SINK_N  16
#define MAXW    160    // >= window(128) + sink(16)
#define MAXC    1904   // >= S - SINK - window
#define MAXT    2048   // unified list capacity (s+1 <= 2048)
#define NREG    32     // ceil(2048/64) unified scores per lane
#define CHUNK   512    // rows scored per LDS chunk
#define MAXSEL  208    // window(144) + top_k(64)
#define PLANE   676    // floats per buf plane (676 % 32 == 4 -> bank-skewed;
                       // holds 512 chunk scores, later 256-u32 hist + 208 u64 sel)

typedef __attribute__((ext_vector_type(8))) short bf16x8;
typedef __attribute__((ext_vector_type(4))) float f32x4;
typedef __attribute__((ext_vector_type(2))) float f32x2;

__device__ __forceinline__ void lds_fence() {
  asm volatile("s_waitcnt lgkmcnt(0)" ::: "memory");
}
__device__ __forceinline__ unsigned int okey(float f) {
  unsigned int b = __float_as_uint(f);
  return (b & 0x80000000u) ? ~b : (b | 0x80000000u);
}
__device__ __forceinline__ float okinv(unsigned int u) {  // inverse of okey
  return __uint_as_float((u & 0x80000000u) ? (u & 0x7fffffffu) : ~u);
}
__device__ __forceinline__ unsigned short f2bf(float f) {  // RNE
  unsigned int u = __float_as_uint(f);
  u += 0x7FFFu + ((u >> 16) & 1u);
  return (unsigned short)(u >> 16);
}
__device__ __forceinline__ float bf2f(unsigned short h) {
  return __uint_as_float(((unsigned int)h) << 16);
}

// ---------------------------------------------------------------------------
// Kernel 1 (k/v only): one wave per 4 rows, row-type uniform per wave.
// [0,8192) k rows: sign words + bf16 hi/lo planes. [8192,16384) v rows:
// packed bf16 plane.
// ---------------------------------------------------------------------------
__global__ __launch_bounds__(256) void pack_kernel(
    const float* __restrict__ k, const float* __restrict__ v,
    unsigned long long* __restrict__ signs,
    unsigned short* __restrict__ kbf, unsigned int* __restrict__ vbf) {
  const int wid  = (blockIdx.x * 256 + threadIdx.x) >> 6;
  const int lane = threadIdx.x & 63;
  const int rbase = wid * 4;
  const int KROWS = KH_N * S_LEN;           // 8192

  if (rbase < KROWS) {
    const float* src = k + (size_t)rbase * D_DIM;
    float a[4], b[4];
#pragma unroll
    for (int r = 0; r < 4; r++) {
      a[r] = src[r * D_DIM + lane];
      b[r] = src[r * D_DIM + 64 + lane];
    }
#pragma unroll
    for (int r = 0; r < 4; r++) {
      unsigned long long b0 = __ballot(a[r] >= 0.0f);
      unsigned long long b1 = __ballot(b[r] >= 0.0f);
      if (lane == 0) {
        signs[(size_t)(rbase + r) * 2]     = b0;
        signs[(size_t)(rbase + r) * 2 + 1] = b1;
      }
      unsigned short h0 = f2bf(a[r]), h1 = f2bf(b[r]);
      unsigned short l0 = f2bf(a[r] - bf2f(h0)), l1 = f2bf(b[r] - bf2f(h1));
      unsigned short* rb = kbf + (size_t)(rbase + r) * 256;  // 128 hi | 128 lo
      rb[lane]       = h0;  rb[64 + lane]  = h1;
      rb[128 + lane] = l0;  rb[192 + lane] = l1;
    }
  } else {
    int vr = rbase - KROWS;
    const float* src = v + (size_t)vr * D_DIM;
    float2 f2[4];
#pragma unroll
    for (int r = 0; r < 4; r++)
      f2[r] = *(const float2*)(src + r * D_DIM + lane * 2);
#pragma unroll
    for (int r = 0; r < 4; r++) {
      unsigned int pk = (unsigned int)f2bf(f2[r].x) |
                        ((unsigned int)f2bf(f2[r].y) << 16);
      vbf[(size_t)(vr + r) * 64 + lane] = pk;
    }
  }
}

// ---------------------------------------------------------------------------
// Kernel 2: one block (4 waves) per (kh, s); wave == qh within the GQA group.
// blockIdx swizzle: xcd = blockIdx&7 (round-robin block->XCD), each kh owned
// by 2 XCDs -> per-XCD L2 working set ~1.5 MB (kbf+vbf slice). Halved
// FETCH_SIZE in round 8.
// __launch_bounds__(256,4): 128-reg combined budget; NO stage-2 prefetch
// (round 8 showed it spills + trades away occupancy at a net loss --
// latency hiding here comes from TLP, not intra-wave ILP).
// ---------------------------------------------------------------------------
__global__ __launch_bounds__(256, 4) void attn_kernel(
    const float* __restrict__ query, const float* __restrict__ thr,
    const int* __restrict__ p_topk, const int* __restrict__ p_wsz,
    const unsigned long long* __restrict__ signs,
    const unsigned short* __restrict__ kbf,
    const unsigned int* __restrict__ vbf,
    float* __restrict__ out) {
  const int xcd  = blockIdx.x & 7;
  const int kh   = xcd >> 1;
  const int s    = (S_LEN - 1) - (((blockIdx.x >> 3) << 1) | (xcd & 1));
  const int tid  = threadIdx.x;
  const int lane = tid & 63;
  const int qh   = tid >> 6;
  const int col  = lane & 15;
  const int quad = lane >> 4;

  __shared__ __align__(16) float buf[QH_N * PLANE];        // 10816 B
  __shared__ __align__(16) unsigned short q_bf[8][136];    // 2176 B
  __shared__ unsigned short idx_sh[MAXT];                  // 4096 B
  __shared__ unsigned long long qs_sh[QH_N][2];
  __shared__ int ncand_sh;
  __shared__ int nsel_sh[QH_N];

  const int   topk   = *p_topk;   // 64
  const int   wsz    = *p_wsz;    // 128
  const float thresh = thr[kh];   // 70.0
  const float scale  = 0.088388347648318447f;  // 1/sqrt(128)

  // ---- load q rows; build q_bf (hi rows 0-3, lo rows 4-7) + q sign words ---
  {
    int h0 = tid >> 7, d = tid & 127;
    float f0 = query[((size_t)(kh * QH_N + h0) * S_LEN + s) * D_DIM + d];
    float f1 = query[((size_t)(kh * QH_N + h0 + 2) * S_LEN + s) * D_DIM + d];
    unsigned long long b0 = __ballot(f0 >= 0.0f);
    unsigned long long b1 = __ballot(f1 >= 0.0f);
    if (lane == 0) {
      qs_sh[qh >> 1][qh & 1] = b0;
      qs_sh[2 + (qh >> 1)][qh & 1] = b1;
    }
    f0 *= scale; f1 *= scale;
    unsigned short hi0 = f2bf(f0), hi1 = f2bf(f1);
    q_bf[h0][d]     = hi0;  q_bf[4 + h0][d]     = f2bf(f0 - bf2f(hi0));
    q_bf[h0 + 2][d] = hi1;  q_bf[4 + h0 + 2][d] = f2bf(f1 - bf2f(hi1));
  }
  if (tid == 0) ncand_sh = 0;

  // ---- window part of the unified list ----
  int wlo = s - (wsz - 1); if (wlo < 0) wlo = 0;
  int nsink = wlo < SINK_N ? wlo : SINK_N;
  int nw = nsink + (s - wlo + 1);
  if (nw > MAXW) nw = MAXW;
  for (int e = tid; e < nw; e += 256)
    idx_sh[e] = (unsigned short)(e < nsink ? e : wlo + (e - nsink));
  __syncthreads();

  // ---- Stage 1: LSH scan over [SINK, s-wsz] -> append candidates at nw ----
  unsigned long long qs0[QH_N], qs1[QH_N];
#pragma unroll
  for (int h = 0; h < QH_N; h++) { qs0[h] = qs_sh[h][0]; qs1[h] = qs_sh[h][1]; }
  const unsigned long long* ksg = signs + (size_t)kh * S_LEN * 2;
  int lt_hi = s - wsz;  // inclusive
  for (int l0 = SINK_N; l0 <= lt_hi; l0 += 256) {
    int l = l0 + tid;
    bool match = false;
    if (l <= lt_hi) {
      ulonglong2 kk = *(const ulonglong2*)(ksg + 2 * l);
      int best = 0;
#pragma unroll
      for (int h = 0; h < QH_N; h++) {
        int m = 128 - __popcll(qs0[h] ^ kk.x) - __popcll(qs1[h] ^ kk.y);
        best = best > m ? best : m;
      }
      match = ((float)best > thresh);
    }
    unsigned long long m = __ballot(match);
    if (m) {
      int base = 0;
      if (lane == 0) base = atomicAdd(&ncand_sh, __popcll(m));
      base = __shfl(base, 0);
      if (match) {
        int pos = base + __popcll(m & ((1ull << lane) - 1ull));
        if (pos < MAXC) idx_sh[nw + pos] = (unsigned short)l;
      }
    }
  }
  __syncthreads();
  int nc = ncand_sh < MAXC ? ncand_sh : MAXC;
  int ntot = nw + nc;
  int ntot_pad = (ntot + 15) & ~15;
  for (int i = ntot + tid; i < ntot_pad; i += 256) idx_sh[i] = 0;
  __syncthreads();

  // ---- Stage 2: MFMA scoring (hi/lo bf16 split), chunked through buf ----
  bf16x8 bfrag[4];
  bf16x8 bzero = {0, 0, 0, 0, 0, 0, 0, 0};
#pragma unroll
  for (int ks = 0; ks < 4; ks++)
    bfrag[ks] = (col < 8) ? *(const bf16x8*)&q_bf[col][ks * 32 + quad * 8] : bzero;

  const unsigned short* kbf_h = kbf + ((size_t)kh << 11) * 256;
  unsigned int creg[NREG];     // ordered-uint score keys (AGPR-resident)
#pragma unroll
  for (int i = 0; i < NREG; i++) creg[i] = 0u;

  for (int cb = 0; cb < 4; cb++) {
    int cbase = cb * CHUNK;
    int chunk_n = ntot_pad - cbase;
    if (chunk_n <= 0) break;
    if (chunk_n > CHUNK) chunk_n = CHUNK;
    int ntiles = chunk_n >> 4;
    for (int t = qh; t < ntiles; t += QH_N) {
      int tb = cbase + t * 16;
      int krow = idx_sh[tb + col];
      const unsigned char* ab =
          (const unsigned char*)(kbf_h + (size_t)krow * 256) + quad * 16;
      bf16x8 ah0 = *(const bf16x8*)(ab + 0);
      bf16x8 ah1 = *(const bf16x8*)(ab + 64);
      bf16x8 ah2 = *(const bf16x8*)(ab + 128);
      bf16x8 ah3 = *(const bf16x8*)(ab + 192);
      bf16x8 al0 = *(const bf16x8*)(ab + 256);
      bf16x8 al1 = *(const bf16x8*)(ab + 320);
      bf16x8 al2 = *(const bf16x8*)(ab + 384);
      bf16x8 al3 = *(const bf16x8*)(ab + 448);
      f32x4 acc = {0.f, 0.f, 0.f, 0.f};
      acc = __builtin_amdgcn_mfma_f32_16x16x32_bf16(ah0, bfrag[0], acc, 0, 0, 0);
      acc = __builtin_amdgcn_mfma_f32_16x16x32_bf16(al0, bfrag[0], acc, 0, 0, 0);
      acc = __builtin_amdgcn_mfma_f32_16x16x32_bf16(ah1, bfrag[1], acc, 0, 0, 0);
      acc = __builtin_amdgcn_mfma_f32_16x16x32_bf16(al1, bfrag[1], acc, 0, 0, 0);
      acc = __builtin_amdgcn_mfma_f32_16x16x32_bf16(ah2, bfrag[2], acc, 0, 0, 0);
      acc = __builtin_amdgcn_mfma_f32_16x16x32_bf16(al2, bfrag[2], acc, 0, 0, 0);
      acc = __builtin_amdgcn_mfma_f32_16x16x32_bf16(ah3, bfrag[3], acc, 0, 0, 0);
      acc = __builtin_amdgcn_mfma_f32_16x16x32_bf16(al3, bfrag[3], acc, 0, 0, 0);
      f32x4 t4;
#pragma unroll
      for (int r = 0; r < 4; r++) t4[r] = acc[r] + __shfl_xor(acc[r], 4);
      if (col < 4)
        *(f32x4*)&buf[col * PLANE + (tb - cbase) + quad * 4] = t4;
    }
    __syncthreads();
#pragma unroll
    for (int j = 0; j < 8; j++) {
      int v = j * 64 + lane;
      if (v < chunk_n) creg[cb * 8 + j] = okey(buf[qh * PLANE + v]);
    }
    __syncthreads();
  }
  const int imax = (ntot + 63) >> 6;

  // per-wave scratch carved from this wave's plane (chunk buffer is dead now)
  unsigned int*       histw = (unsigned int*)&buf[qh * PLANE];           // 256 u32
  unsigned long long* selq  = (unsigned long long*)&buf[qh * PLANE + 256]; // 208 u64

  // ---- cheap exact max: max over ALL scores == max over included set ----
  unsigned int mxu = 0;
#pragma unroll
  for (int i = 0; i < NREG; i++) {
    if (i >= imax) break;
    int e = lane + i * 64;
    if (e < ntot && creg[i] > mxu) mxu = creg[i];
  }
#pragma unroll
  for (int off = 32; off > 0; off >>= 1) {
    unsigned int t = __shfl_down(mxu, off);
    mxu = t > mxu ? t : mxu;
  }
  mxu = __shfl(mxu, 0);
  const float mxf = okinv(mxu);

  // ---- Stage 3: per-wave exact top-k threshold (radix-256, 4 passes) ----
  bool selAll = (nc <= topk);
  unsigned int tkey = 0;
  bool useTie = false;
  int l_cut = S_LEN;
  if (!selAll) {
    unsigned int prefix = 0;
    int want = topk;
    for (int pass = 0; pass < 4; pass++) {
      int sh = 24 - pass * 8;
#pragma unroll
      for (int j = 0; j < 4; j++) histw[lane * 4 + j] = 0;
      lds_fence();
#pragma unroll
      for (int i = 0; i < NREG; i++) {
        if (i >= imax) break;
        int e = lane + i * 64;
        if (e >= nw && e < ntot) {
          unsigned int u = creg[i];
          bool match = (pass == 0) || ((u >> (sh + 8)) == prefix);
          if (match) atomicAdd(&histw[(u >> sh) & 255u], 1u);
        }
      }
      lds_fence();
      unsigned int c0 = histw[lane * 4 + 0];
      unsigned int c1 = histw[lane * 4 + 1];
      unsigned int c2 = histw[lane * 4 + 2];
      unsigned int c3 = histw[lane * 4 + 3];
      unsigned int S3 = c3, S2 = c2 + S3, S1 = c1 + S2, S0 = c0 + S1;
      unsigned int tot = S0;
      unsigned int suf = tot;
#pragma unroll
      for (int off = 1; off < 64; off <<= 1) {
        unsigned int t = __shfl_down(suf, off);
        if (lane + off < 64) suf += t;
      }
      unsigned long long mk = __ballot(suf >= (unsigned int)want);
      int L = 63 - __clzll(mk);
      unsigned int se = suf - tot;
      unsigned int s3 = S3 + se, s2 = S2 + se, s1 = S1 + se, s0 = S0 + se;
      int j; unsigned int above;
      unsigned int w = (unsigned int)want;
      if (s3 >= w)      { j = 3; above = s3 - c3; }
      else if (s2 >= w) { j = 2; above = s2 - c2; }
      else if (s1 >= w) { j = 1; above = s1 - c1; }
      else              { j = 0; above = s0 - c0; }
      int d_me = (lane << 2) | j;
      int wp_me = want - (int)above;
      int digit = __shfl(d_me, L);
      want = __shfl(wp_me, L);
      prefix = (prefix << 8) | (unsigned int)digit;
    }
    tkey = prefix;
    // exact tie handling (lowest l wins, matching lax.top_k)
    int cgt = 0, ceq = 0;
#pragma unroll
    for (int i = 0; i < NREG; i++) {
      if (i >= imax) break;
      int e = lane + i * 64;
      if (e >= nw && e < ntot) {
        cgt += (creg[i] > tkey);
        ceq += (creg[i] == tkey);
      }
    }
#pragma unroll
    for (int off = 32; off > 0; off >>= 1) {
      cgt += __shfl_down(cgt, off);
      ceq += __shfl_down(ceq, off);
    }
    cgt = __shfl(cgt, 0); ceq = __shfl(ceq, 0);
    int rem = topk - cgt;
    if (ceq > rem) {
      useTie = true;
      int lo = 0, hi = S_LEN - 1;
      while (lo < hi) {
        int mid = (lo + hi) >> 1;
        int cn = 0;
#pragma unroll
        for (int i = 0; i < NREG; i++) {
          if (i >= imax) break;
          int e = lane + i * 64;
          if (e >= nw && e < ntot)
            cn += (creg[i] == tkey && (int)idx_sh[e] <= mid);
        }
#pragma unroll
        for (int off = 32; off > 0; off >>= 1) cn += __shfl_down(cn, off);
        cn = __shfl(cn, 0);
        if (cn >= rem) hi = mid; else lo = mid + 1;
      }
      l_cut = lo;
    }
  }

  // ---- Stage 4: fused select + exp + ballot-compact (single pass) ----
  if (lane == 0) nsel_sh[qh] = 0;
  lds_fence();
  float sum = 0.0f;
#pragma unroll
  for (int i = 0; i < NREG; i++) {
    if (i >= imax) break;
    int e = lane + i * 64;
    bool act = false;
    float p = 0.f;
    if (e < ntot) {
      unsigned int u = creg[i];
      bool inc = (e < nw) || selAll;
      if (!inc)
        inc = (u > tkey) || (u == tkey && (!useTie || (int)idx_sh[e] <= l_cut));
      if (inc) { act = true; p = __expf(okinv(u) - mxf); sum += p; }
    }
    unsigned long long m = __ballot(act);
    if (m) {
      int base = 0;
      if (lane == 0) base = atomicAdd(&nsel_sh[qh], __popcll(m));
      base = __shfl(base, 0);
      if (act) {
        int pi = base + __popcll(m & ((1ull << lane) - 1ull));
        selq[pi] = ((unsigned long long)idx_sh[e] << 32) |
                   (unsigned long long)__float_as_uint(p);
      }
    }
  }
#pragma unroll
  for (int off = 32; off > 0; off >>= 1) sum += __shfl_down(sum, off);
  sum = __shfl(sum, 0);
  float rinv = 1.0f / sum;

  lds_fence();
  int nsel = nsel_sh[qh];
  int nsel8 = (nsel + 7) & ~7;
  if (lane < nsel8 - nsel) selq[nsel + lane] = 0ull;  // pad: p=0, idx=0
  lds_fence();

  // ---- Stage 5: PV accumulate over bf16 V, 8-way unrolled ----
  float accx = 0.f, accy = 0.f;
  const unsigned int* vb = vbf + ((size_t)kh << 11) * 64 + lane;
  for (int e = 0; e < nsel8; e += 8) {
    unsigned long long q8[8];
#pragma unroll
    for (int j = 0; j < 8; j++) q8[j] = selq[e + j];
    unsigned int dv[8]; float pv[8];
#pragma unroll
    for (int j = 0; j < 8; j++) {
      pv[j] = __uint_as_float((unsigned int)q8[j]);
      dv[j] = vb[(size_t)(q8[j] >> 32) * 64];
    }
#pragma unroll
    for (int j = 0; j < 8; j++) {
      accx += pv[j] * __uint_as_float(dv[j] << 16);
      accy += pv[j] * __uint_as_float(dv[j] & 0xFFFF0000u);
    }
  }
  size_t o = (size_t)s * (H_N * D_DIM) + (size_t)(kh * QH_N + qh) * D_DIM + lane * 2;
  f32x2 res = {accx * rinv, accy * rinv};
  __builtin_nontemporal_store(res, (f32x2*)(out + o));
}

// ---------------------------------------------------------------------------
extern "C" void kernel_launch(void* const* d_in, const int* in_sizes, int n_in,
                              void* d_out, int out_size, void* d_ws, size_t ws_size,
                              hipStream_t stream) {
  const float* query = (const float*)d_in[0];
  const float* key   = (const float*)d_in[1];
  const float* value = (const float*)d_in[2];
  const float* thr   = (const float*)d_in[3];
  const int* p_topk  = (const int*)d_in[4];
  const int* p_wsz   = (const int*)d_in[5];
  float* out = (float*)d_out;

  // ws layout: k-signs 8192*16B = 128 KB | kbf 8192*512B = 4 MB | vbf 8192*256B = 2 MB
  char* ws = (char*)d_ws;
  unsigned long long* signs = (unsigned long long*)ws;
  unsigned short* kbf = (unsigned short*)(ws + (size_t)KH_N * S_LEN * 16);
  unsigned int* vbf = (unsigned int*)(ws + (size_t)KH_N * S_LEN * 16
                                         + (size_t)KH_N * S_LEN * 512);

  // 16384 k+v rows, 4 rows/wave, 4 waves/block -> 1024 blocks
  pack_kernel<<<1024, 256, 0, stream>>>(key, value, signs, kbf, vbf);

  attn_kernel<<<KH_N * S_LEN, 256, 0, stream>>>(
      query, thr, p_topk, p_wsz, signs, kbf, vbf, out);
}

// Round 10
// 316.818 us; speedup vs baseline: 1.3901x; 1.2643x over previous
//
#include <hip/hip_runtime.h>

// Problem constants (fixed by setup_inputs)
#define S_LEN   2048
#define D_DIM   128
#define KH_N    4
#define QH_N    4
#define H_N     (KH_N * QH_N)
#define SINK_N  16
#define MAXW    160    // >= window(128) + sink(16)
#define MAXC    1904   // >= S - SINK - window
#define MAXT    2048   // unified list capacity (s+1 <= 2048)
#define NREG    32     // ceil(2048/64) unified scores per lane
#define CHUNK   512    // rows scored per LDS chunk
#define MAXSEL  208    // window(144) + top_k(64)
#define PLANE   676    // floats per buf plane (676 % 32 == 4 -> bank-skewed;
                       // holds 512 chunk scores, later 256-u32 hist + 208 u64 sel)

typedef __attribute__((ext_vector_type(8))) _Float16 f16x8;
typedef __attribute__((ext_vector_type(4))) float f32x4;
typedef __attribute__((ext_vector_type(2))) float f32x2;

__device__ __forceinline__ void lds_fence() {
  asm volatile("s_waitcnt lgkmcnt(0)" ::: "memory");
}
__device__ __forceinline__ unsigned int okey(float f) {
  unsigned int b = __float_as_uint(f);
  return (b & 0x80000000u) ? ~b : (b | 0x80000000u);
}
__device__ __forceinline__ float okinv(unsigned int u) {  // inverse of okey
  return __uint_as_float((u & 0x80000000u) ? (u & 0x7fffffffu) : ~u);
}
__device__ __forceinline__ unsigned short f2h(float f) {  // fp32 -> fp16 RNE
  _Float16 h = (_Float16)f;
  return __builtin_bit_cast(unsigned short, h);
}
__device__ __forceinline__ float h2f(unsigned int u) {    // low 16 bits -> fp32
  return (float)__builtin_bit_cast(_Float16, (unsigned short)(u & 0xFFFFu));
}

// ---------------------------------------------------------------------------
// Kernel 1 (k/v only): one wave per 4 rows, row-type uniform per wave.
// [0,8192) k rows: sign words + fp16 plane (256 B/row).
// [8192,16384) v rows: fp16 plane (2 dims packed per u32).
// fp16 everywhere: scores only need ~3e-4 accuracy (softmax boundary weight is
// ~e^-10 thanks to the self-attention diagonal), while V accuracy directly
// bounds output error (fp16 2^-12 beats the old bf16 2^-9 by 8x).
// ---------------------------------------------------------------------------
__global__ __launch_bounds__(256) void pack_kernel(
    const float* __restrict__ k, const float* __restrict__ v,
    unsigned long long* __restrict__ signs,
    unsigned short* __restrict__ kf16, unsigned int* __restrict__ vf16) {
  const int wid  = (blockIdx.x * 256 + threadIdx.x) >> 6;
  const int lane = threadIdx.x & 63;
  const int rbase = wid * 4;
  const int KROWS = KH_N * S_LEN;           // 8192

  if (rbase < KROWS) {
    const float* src = k + (size_t)rbase * D_DIM;
    float a[4], b[4];
#pragma unroll
    for (int r = 0; r < 4; r++) {
      a[r] = src[r * D_DIM + lane];
      b[r] = src[r * D_DIM + 64 + lane];
    }
#pragma unroll
    for (int r = 0; r < 4; r++) {
      unsigned long long b0 = __ballot(a[r] >= 0.0f);
      unsigned long long b1 = __ballot(b[r] >= 0.0f);
      if (lane == 0) {
        signs[(size_t)(rbase + r) * 2]     = b0;
        signs[(size_t)(rbase + r) * 2 + 1] = b1;
      }
      unsigned short* rb = kf16 + (size_t)(rbase + r) * 128;
      rb[lane]      = f2h(a[r]);
      rb[64 + lane] = f2h(b[r]);
    }
  } else {
    int vr = rbase - KROWS;
    const float* src = v + (size_t)vr * D_DIM;
    float2 f2[4];
#pragma unroll
    for (int r = 0; r < 4; r++)
      f2[r] = *(const float2*)(src + r * D_DIM + lane * 2);
#pragma unroll
    for (int r = 0; r < 4; r++) {
      unsigned int pk = (unsigned int)f2h(f2[r].x) |
                        ((unsigned int)f2h(f2[r].y) << 16);
      vf16[(size_t)(vr + r) * 64 + lane] = pk;
    }
  }
}

// ---------------------------------------------------------------------------
// Kernel 2: one block (4 waves) per (kh, s); wave == qh within the GQA group.
// blockIdx swizzle: xcd = blockIdx&7 -> each kh owned by 2 XCDs (L2 locality).
// __launch_bounds__(256,4): 128-reg combined budget (no spill; (256,8) spilled
// in round 6; stage-2 prefetch spilled in round 8 -- TLP beats ILP here).
// fp16 MFMA: heads live directly in B cols 0-3 -> score = acc[r], no shfl.
// ---------------------------------------------------------------------------
__global__ __launch_bounds__(256, 4) void attn_kernel(
    const float* __restrict__ query, const float* __restrict__ thr,
    const int* __restrict__ p_topk, const int* __restrict__ p_wsz,
    const unsigned long long* __restrict__ signs,
    const unsigned short* __restrict__ kf16,
    const unsigned int* __restrict__ vf16,
    float* __restrict__ out) {
  const int xcd  = blockIdx.x & 7;
  const int kh   = xcd >> 1;
  const int s    = (S_LEN - 1) - (((blockIdx.x >> 3) << 1) | (xcd & 1));
  const int tid  = threadIdx.x;
  const int lane = tid & 63;
  const int qh   = tid >> 6;
  const int col  = lane & 15;
  const int quad = lane >> 4;

  __shared__ __align__(16) float buf[QH_N * PLANE];        // 10816 B
  __shared__ __align__(16) unsigned short q_f16[QH_N][136];// 1088 B
  __shared__ unsigned short idx_sh[MAXT];                  // 4096 B
  __shared__ unsigned long long qs_sh[QH_N][2];
  __shared__ int ncand_sh;

  const int   topk   = *p_topk;   // 64
  const int   wsz    = *p_wsz;    // 128
  const float thresh = thr[kh];   // 70.0
  const float scale  = 0.088388347648318447f;  // 1/sqrt(128)

  // ---- load q rows; build q_f16 + q sign words (ballot == sign word) ----
  {
    int h0 = tid >> 7, d = tid & 127;
    float f0 = query[((size_t)(kh * QH_N + h0) * S_LEN + s) * D_DIM + d];
    float f1 = query[((size_t)(kh * QH_N + h0 + 2) * S_LEN + s) * D_DIM + d];
    unsigned long long b0 = __ballot(f0 >= 0.0f);
    unsigned long long b1 = __ballot(f1 >= 0.0f);
    if (lane == 0) {
      qs_sh[qh >> 1][qh & 1] = b0;
      qs_sh[2 + (qh >> 1)][qh & 1] = b1;
    }
    q_f16[h0][d]     = f2h(f0 * scale);
    q_f16[h0 + 2][d] = f2h(f1 * scale);
  }
  if (tid == 0) ncand_sh = 0;

  // ---- window part of the unified list ----
  int wlo = s - (wsz - 1); if (wlo < 0) wlo = 0;
  int nsink = wlo < SINK_N ? wlo : SINK_N;
  int nw = nsink + (s - wlo + 1);
  if (nw > MAXW) nw = MAXW;
  for (int e = tid; e < nw; e += 256)
    idx_sh[e] = (unsigned short)(e < nsink ? e : wlo + (e - nsink));
  __syncthreads();

  // ---- Stage 1: LSH scan over [SINK, s-wsz] -> append candidates at nw ----
  unsigned long long qs0[QH_N], qs1[QH_N];
#pragma unroll
  for (int h = 0; h < QH_N; h++) { qs0[h] = qs_sh[h][0]; qs1[h] = qs_sh[h][1]; }
  const unsigned long long* ksg = signs + (size_t)kh * S_LEN * 2;
  int lt_hi = s - wsz;  // inclusive
  for (int l0 = SINK_N; l0 <= lt_hi; l0 += 256) {
    int l = l0 + tid;
    bool match = false;
    if (l <= lt_hi) {
      ulonglong2 kk = *(const ulonglong2*)(ksg + 2 * l);
      int best = 0;
#pragma unroll
      for (int h = 0; h < QH_N; h++) {
        int m = 128 - __popcll(qs0[h] ^ kk.x) - __popcll(qs1[h] ^ kk.y);
        best = best > m ? best : m;
      }
      match = ((float)best > thresh);
    }
    unsigned long long m = __ballot(match);
    if (m) {
      int base = 0;
      if (lane == 0) base = atomicAdd(&ncand_sh, __popcll(m));
      base = __shfl(base, 0);
      if (match) {
        int pos = base + __popcll(m & ((1ull << lane) - 1ull));
        if (pos < MAXC) idx_sh[nw + pos] = (unsigned short)l;
      }
    }
  }
  __syncthreads();
  int nc = ncand_sh < MAXC ? ncand_sh : MAXC;
  int ntot = nw + nc;
  int ntot_pad = (ntot + 15) & ~15;
  for (int i = ntot + tid; i < ntot_pad; i += 256) idx_sh[i] = 0;
  __syncthreads();

  // ---- Stage 2: fp16 MFMA scoring, chunked through buf ----
  // B cols 0-3 = q heads (scale folded), cols 4-15 = 0; score[m][h] = acc.
  f16x8 bfrag[4];
  f16x8 bzero = {0, 0, 0, 0, 0, 0, 0, 0};
#pragma unroll
  for (int ks = 0; ks < 4; ks++)
    bfrag[ks] = (col < 4) ? *(const f16x8*)&q_f16[col][ks * 32 + quad * 8] : bzero;

  const unsigned short* kf_h = kf16 + ((size_t)kh << 11) * 128;
  unsigned int creg[NREG];     // ordered-uint score keys
#pragma unroll
  for (int i = 0; i < NREG; i++) creg[i] = 0u;

  for (int cb = 0; cb < 4; cb++) {
    int cbase = cb * CHUNK;
    int chunk_n = ntot_pad - cbase;
    if (chunk_n <= 0) break;
    if (chunk_n > CHUNK) chunk_n = CHUNK;
    int ntiles = chunk_n >> 4;
    for (int t = qh; t < ntiles; t += QH_N) {
      int tb = cbase + t * 16;
      int krow = idx_sh[tb + col];
      const unsigned char* ab =
          (const unsigned char*)(kf_h + (size_t)krow * 128) + quad * 16;
      f16x8 a0 = *(const f16x8*)(ab + 0);
      f16x8 a1 = *(const f16x8*)(ab + 64);
      f16x8 a2 = *(const f16x8*)(ab + 128);
      f16x8 a3 = *(const f16x8*)(ab + 192);
      f32x4 acc = {0.f, 0.f, 0.f, 0.f};
      acc = __builtin_amdgcn_mfma_f32_16x16x32_f16(a0, bfrag[0], acc, 0, 0, 0);
      acc = __builtin_amdgcn_mfma_f32_16x16x32_f16(a1, bfrag[1], acc, 0, 0, 0);
      acc = __builtin_amdgcn_mfma_f32_16x16x32_f16(a2, bfrag[2], acc, 0, 0, 0);
      acc = __builtin_amdgcn_mfma_f32_16x16x32_f16(a3, bfrag[3], acc, 0, 0, 0);
      if (col < 4)
        *(f32x4*)&buf[col * PLANE + (tb - cbase) + quad * 4] = acc;
    }
    __syncthreads();
#pragma unroll
    for (int j = 0; j < 8; j++) {
      int v = j * 64 + lane;
      if (v < chunk_n) creg[cb * 8 + j] = okey(buf[qh * PLANE + v]);
    }
    __syncthreads();
  }
  const int imax = (ntot + 63) >> 6;

  // per-wave scratch carved from this wave's plane (chunk buffer is dead now)
  unsigned int*       histw = (unsigned int*)&buf[qh * PLANE];           // 256 u32
  unsigned long long* selq  = (unsigned long long*)&buf[qh * PLANE + 256]; // 208 u64

  // ---- cheap exact max: max over ALL scores == max over included set ----
  unsigned int mxu = 0;
#pragma unroll
  for (int i = 0; i < NREG; i++) {
    if (i >= imax) break;
    int e = lane + i * 64;
    if (e < ntot && creg[i] > mxu) mxu = creg[i];
  }
#pragma unroll
  for (int off = 32; off > 0; off >>= 1) {
    unsigned int t = __shfl_down(mxu, off);
    mxu = t > mxu ? t : mxu;
  }
  mxu = __shfl(mxu, 0);
  const float mxf = okinv(mxu);

  // ---- Stage 3: per-wave exact top-k threshold (radix-256, 4 passes) ----
  bool selAll = (nc <= topk);
  unsigned int tkey = 0;
  bool useTie = false;
  int l_cut = S_LEN;
  if (!selAll) {
    unsigned int prefix = 0;
    int want = topk;
    for (int pass = 0; pass < 4; pass++) {
      int sh = 24 - pass * 8;
#pragma unroll
      for (int j = 0; j < 4; j++) histw[lane * 4 + j] = 0;
      lds_fence();
#pragma unroll
      for (int i = 0; i < NREG; i++) {
        if (i >= imax) break;
        int e = lane + i * 64;
        if (e >= nw && e < ntot) {
          unsigned int u = creg[i];
          bool match = (pass == 0) || ((u >> (sh + 8)) == prefix);
          if (match) atomicAdd(&histw[(u >> sh) & 255u], 1u);
        }
      }
      lds_fence();
      unsigned int c0 = histw[lane * 4 + 0];
      unsigned int c1 = histw[lane * 4 + 1];
      unsigned int c2 = histw[lane * 4 + 2];
      unsigned int c3 = histw[lane * 4 + 3];
      unsigned int S3 = c3, S2 = c2 + S3, S1 = c1 + S2, S0 = c0 + S1;
      unsigned int tot = S0;
      unsigned int suf = tot;
#pragma unroll
      for (int off = 1; off < 64; off <<= 1) {
        unsigned int t = __shfl_down(suf, off);
        if (lane + off < 64) suf += t;
      }
      unsigned long long mk = __ballot(suf >= (unsigned int)want);
      int L = 63 - __clzll(mk);
      unsigned int se = suf - tot;
      unsigned int s3 = S3 + se, s2 = S2 + se, s1 = S1 + se, s0 = S0 + se;
      int j; unsigned int above;
      unsigned int w = (unsigned int)want;
      if (s3 >= w)      { j = 3; above = s3 - c3; }
      else if (s2 >= w) { j = 2; above = s2 - c2; }
      else if (s1 >= w) { j = 1; above = s1 - c1; }
      else              { j = 0; above = s0 - c0; }
      int d_me = (lane << 2) | j;
      int wp_me = want - (int)above;
      int digit = __shfl(d_me, L);
      want = __shfl(wp_me, L);
      prefix = (prefix << 8) | (unsigned int)digit;
    }
    tkey = prefix;
    // exact tie handling (lowest l wins, matching lax.top_k)
    int cgt = 0, ceq = 0;
#pragma unroll
    for (int i = 0; i < NREG; i++) {
      if (i >= imax) break;
      int e = lane + i * 64;
      if (e >= nw && e < ntot) {
        cgt += (creg[i] > tkey);
        ceq += (creg[i] == tkey);
      }
    }
#pragma unroll
    for (int off = 32; off > 0; off >>= 1) {
      cgt += __shfl_down(cgt, off);
      ceq += __shfl_down(ceq, off);
    }
    cgt = __shfl(cgt, 0); ceq = __shfl(ceq, 0);
    int rem = topk - cgt;
    if (ceq > rem) {
      useTie = true;
      int lo = 0, hi = S_LEN - 1;
      while (lo < hi) {
        int mid = (lo + hi) >> 1;
        int cn = 0;
#pragma unroll
        for (int i = 0; i < NREG; i++) {
          if (i >= imax) break;
          int e = lane + i * 64;
          if (e >= nw && e < ntot)
            cn += (creg[i] == tkey && (int)idx_sh[e] <= mid);
        }
#pragma unroll
        for (int off = 32; off > 0; off >>= 1) cn += __shfl_down(cn, off);
        cn = __shfl(cn, 0);
        if (cn >= rem) hi = mid; else lo = mid + 1;
      }
      l_cut = lo;
    }
  }

  // ---- Stage 4: fused select + exp + compact (running register base) ----
  float sum = 0.0f;
  int base = 0;
#pragma unroll
  for (int i = 0; i < NREG; i++) {
    if (i >= imax) break;
    int e = lane + i * 64;
    bool act = false;
    float p = 0.f;
    if (e < ntot) {
      unsigned int u = creg[i];
      bool inc = (e < nw) || selAll;
      if (!inc)
        inc = (u > tkey) || (u == tkey && (!useTie || (int)idx_sh[e] <= l_cut));
      if (inc) { act = true; p = __expf(okinv(u) - mxf); sum += p; }
    }
    unsigned long long m = __ballot(act);
    if (act) {
      int pi = base + __popcll(m & ((1ull << lane) - 1ull));
      selq[pi] = ((unsigned long long)idx_sh[e] << 32) |
                 (unsigned long long)__float_as_uint(p);
    }
    base += (int)__popcll(m);
  }
#pragma unroll
  for (int off = 32; off > 0; off >>= 1) sum += __shfl_down(sum, off);
  sum = __shfl(sum, 0);
  float rinv = 1.0f / sum;

  int nsel = base;
  int nsel8 = (nsel + 7) & ~7;
  if (lane < nsel8 - nsel) selq[nsel + lane] = 0ull;  // pad: p=0, idx=0
  lds_fence();

  // ---- Stage 5: PV over fp16 V; half-wave entry parity, 4 dims/lane ----
  // lanes 0-31 take even entries, 32-63 odd; lane owns dims 4L..4L+3 (L=lane&31)
  float a0 = 0.f, a1 = 0.f, a2 = 0.f, a3 = 0.f;
  const int half = lane >> 5;
  const unsigned int* vb = vf16 + ((size_t)kh << 11) * 64 + (lane & 31) * 2;
  for (int e = 0; e < nsel8; e += 8) {
#pragma unroll
    for (int j = 0; j < 4; j++) {
      unsigned long long q8 = selq[e + 2 * j + half];
      float p = __uint_as_float((unsigned int)q8);
      int l = (int)(q8 >> 32);
      uint2 dv = *(const uint2*)(vb + (size_t)l * 64);
      a0 += p * h2f(dv.x);
      a1 += p * h2f(dv.x >> 16);
      a2 += p * h2f(dv.y);
      a3 += p * h2f(dv.y >> 16);
    }
  }
  a0 += __shfl_xor(a0, 32);
  a1 += __shfl_xor(a1, 32);
  a2 += __shfl_xor(a2, 32);
  a3 += __shfl_xor(a3, 32);
  if (lane < 32) {
    size_t o = (size_t)s * (H_N * D_DIM) + (size_t)(kh * QH_N + qh) * D_DIM
             + (size_t)lane * 4;
    f32x4 res = {a0 * rinv, a1 * rinv, a2 * rinv, a3 * rinv};
    __builtin_nontemporal_store(res, (f32x4*)(out + o));
  }
}

// ---------------------------------------------------------------------------
extern "C" void kernel_launch(void* const* d_in, const int* in_sizes, int n_in,
                              void* d_out, int out_size, void* d_ws, size_t ws_size,
                              hipStream_t stream) {
  const float* query = (const float*)d_in[0];
  const float* key   = (const float*)d_in[1];
  const float* value = (const float*)d_in[2];
  const float* thr   = (const float*)d_in[3];
  const int* p_topk  = (const int*)d_in[4];
  const int* p_wsz   = (const int*)d_in[5];
  float* out = (float*)d_out;

  // ws: k-signs 8192*16B = 128 KB | kf16 8192*256B = 2 MB | vf16 8192*256B = 2 MB
  char* ws = (char*)d_ws;
  unsigned long long* signs = (unsigned long long*)ws;
  unsigned short* kf16 = (unsigned short*)(ws + (size_t)KH_N * S_LEN * 16);
  unsigned int* vf16 = (unsigned int*)(ws + (size_t)KH_N * S_LEN * 16
                                          + (size_t)KH_N * S_LEN * 256);

  // 16384 k+v rows, 4 rows/wave, 4 waves/block -> 1024 blocks
  pack_kernel<<<1024, 256, 0, stream>>>(key, value, signs, kf16, vf16);

  attn_kernel<<<KH_N * S_LEN, 256, 0, stream>>>(
      query, thr, p_topk, p_wsz, signs, kf16, vf16, out);
}

// Round 12
// 251.532 us; speedup vs baseline: 1.7509x; 1.2596x over previous
//
#include <hip/hip_runtime.h>

// Problem constants (fixed by setup_inputs)
#define S_LEN   2048
#define D_DIM   128
#define KH_N    4
#define QH_N    4
#define H_N     (KH_N * QH_N)
#define SINK_N  16
#define MAXW    160    // >= window(128) + sink(16)
#define MAXC    1904   // >= S - SINK - window
#define MAXT    2048   // unified list capacity (s+1 <= 2048)
#define NREG    16     // u32 regs, 2 fp16 ordered keys each -> 2048 entries
#define CHUNK   512    // rows scored per LDS chunk
#define MAXSEL  208    // window(144) + top_k(64)
#define PLANE32 676    // u32 per plane (676 % 32 == 4 -> bank-skewed);
                       // phase A: 256 u32 packed chunk keys
                       // phase B: hist 256 u32 | selq 208 u64 (@ +256)

typedef __attribute__((ext_vector_type(8))) _Float16 f16x8;
typedef __attribute__((ext_vector_type(2))) _Float16 f16x2;
typedef __attribute__((ext_vector_type(4))) float f32x4;

__device__ __forceinline__ void lds_fence() {
  asm volatile("s_waitcnt lgkmcnt(0)" ::: "memory");
}
__device__ __forceinline__ unsigned short f2h(float f) {
  _Float16 h = (_Float16)f;
  return __builtin_bit_cast(unsigned short, h);
}
// pack two fp32 -> two fp16 (RTZ) as u32
__device__ __forceinline__ unsigned int pkrtz_u32(float a, float b) {
  return __builtin_bit_cast(unsigned int, __builtin_amdgcn_cvt_pkrtz(a, b));
}
// pack two fp32 scores -> two 16-bit ordered keys (monotone with value)
__device__ __forceinline__ unsigned int pack_okey16(float a, float b) {
  unsigned int u = pkrtz_u32(a, b);
  unsigned int t = (u >> 15) & 0x00010001u;
  return u ^ ((t * 0x7FFFu) | 0x80008000u);
}
__device__ __forceinline__ float okinv16(unsigned int k) {  // k in low 16 bits
  unsigned short bits = (k & 0x8000u) ? (unsigned short)(k & 0x7FFFu)
                                      : (unsigned short)(~k & 0xFFFFu);
  return (float)__builtin_bit_cast(_Float16, bits);
}

// ---------------------------------------------------------------------------
// Kernel 1 (k/v only): one wave per 4 rows, row-type uniform per wave.
// [0,8192) k rows: sign words + fp16 plane. [8192,16384) v rows: fp16 plane.
// ---------------------------------------------------------------------------
__global__ __launch_bounds__(256) void pack_kernel(
    const float* __restrict__ k, const float* __restrict__ v,
    unsigned long long* __restrict__ signs,
    unsigned short* __restrict__ kf16, unsigned int* __restrict__ vf16) {
  const int wid  = (blockIdx.x * 256 + threadIdx.x) >> 6;
  const int lane = threadIdx.x & 63;
  const int rbase = wid * 4;
  const int KROWS = KH_N * S_LEN;           // 8192

  if (rbase < KROWS) {
    const float* src = k + (size_t)rbase * D_DIM;
    float a[4], b[4];
#pragma unroll
    for (int r = 0; r < 4; r++) {
      a[r] = src[r * D_DIM + lane];
      b[r] = src[r * D_DIM + 64 + lane];
    }
#pragma unroll
    for (int r = 0; r < 4; r++) {
      unsigned long long b0 = __ballot(a[r] >= 0.0f);
      unsigned long long b1 = __ballot(b[r] >= 0.0f);
      if (lane == 0) {
        signs[(size_t)(rbase + r) * 2]     = b0;
        signs[(size_t)(rbase + r) * 2 + 1] = b1;
      }
      unsigned short* rb = kf16 + (size_t)(rbase + r) * 128;
      rb[lane]      = f2h(a[r]);
      rb[64 + lane] = f2h(b[r]);
    }
  } else {
    int vr = rbase - KROWS;
    const float* src = v + (size_t)vr * D_DIM;
    float2 f2[4];
#pragma unroll
    for (int r = 0; r < 4; r++)
      f2[r] = *(const float2*)(src + r * D_DIM + lane * 2);
#pragma unroll
    for (int r = 0; r < 4; r++) {
      unsigned int pk = (unsigned int)f2h(f2[r].x) |
                        ((unsigned int)f2h(f2[r].y) << 16);
      vf16[(size_t)(vr + r) * 64 + lane] = pk;
    }
  }
}

// ---------------------------------------------------------------------------
// Kernel 2: one block (4 waves) per (kh, s); wave == qh within the GQA group.
// xcd swizzle (blockIdx&7) -> each kh owned by 2 XCDs (halved FETCH in r8).
// fp16 packed score keys: NREG=16, radix-256 in 2 passes.
// __launch_bounds__(256,5): ~102-reg cap; kernel needs ~80 (no spill;
// (256,8)=64-cap spilled in r6 -- watch WRITE_SIZE).
// ---------------------------------------------------------------------------
__global__ __launch_bounds__(256, 5) void attn_kernel(
    const float* __restrict__ query, const float* __restrict__ thr,
    const int* __restrict__ p_topk, const int* __restrict__ p_wsz,
    const unsigned long long* __restrict__ signs,
    const unsigned short* __restrict__ kf16,
    const unsigned int* __restrict__ vf16,
    float* __restrict__ out) {
  const int xcd  = blockIdx.x & 7;
  const int kh   = xcd >> 1;
  const int s    = (S_LEN - 1) - (((blockIdx.x >> 3) << 1) | (xcd & 1));
  const int tid  = threadIdx.x;
  const int lane = tid & 63;
  const int qh   = tid >> 6;
  const int col  = lane & 15;
  const int quad = lane >> 4;

  __shared__ __align__(16) unsigned int buf[QH_N * PLANE32]; // 10816 B
  __shared__ __align__(16) unsigned short q_f16[QH_N][136];  // 1088 B
  __shared__ unsigned short idx_sh[MAXT];                    // 4096 B
  __shared__ unsigned long long qs_sh[QH_N][2];
  __shared__ int ncand_sh;

  const int   topk   = *p_topk;   // 64
  const int   wsz    = *p_wsz;    // 128
  const float thresh = thr[kh];   // 70.0
  const float scale  = 0.088388347648318447f;  // 1/sqrt(128)

  // ---- load q rows; build q_f16 + q sign words (ballot == sign word) ----
  {
    int h0 = tid >> 7, d = tid & 127;
    float f0 = query[((size_t)(kh * QH_N + h0) * S_LEN + s) * D_DIM + d];
    float f1 = query[((size_t)(kh * QH_N + h0 + 2) * S_LEN + s) * D_DIM + d];
    unsigned long long b0 = __ballot(f0 >= 0.0f);
    unsigned long long b1 = __ballot(f1 >= 0.0f);
    if (lane == 0) {
      qs_sh[qh >> 1][qh & 1] = b0;
      qs_sh[2 + (qh >> 1)][qh & 1] = b1;
    }
    q_f16[h0][d]     = f2h(f0 * scale);
    q_f16[h0 + 2][d] = f2h(f1 * scale);
  }
  if (tid == 0) ncand_sh = 0;

  // ---- window part of the unified list ----
  int wlo = s - (wsz - 1); if (wlo < 0) wlo = 0;
  int nsink = wlo < SINK_N ? wlo : SINK_N;
  int nw = nsink + (s - wlo + 1);
  if (nw > MAXW) nw = MAXW;
  for (int e = tid; e < nw; e += 256)
    idx_sh[e] = (unsigned short)(e < nsink ? e : wlo + (e - nsink));
  __syncthreads();

  // ---- Stage 1: LSH scan over [SINK, s-wsz] -> append candidates at nw ----
  unsigned long long qs0[QH_N], qs1[QH_N];
#pragma unroll
  for (int h = 0; h < QH_N; h++) { qs0[h] = qs_sh[h][0]; qs1[h] = qs_sh[h][1]; }
  const unsigned long long* ksg = signs + (size_t)kh * S_LEN * 2;
  int lt_hi = s - wsz;  // inclusive
  for (int l0 = SINK_N; l0 <= lt_hi; l0 += 256) {
    int l = l0 + tid;
    bool match = false;
    if (l <= lt_hi) {
      ulonglong2 kk = *(const ulonglong2*)(ksg + 2 * l);
      int best = 0;
#pragma unroll
      for (int h = 0; h < QH_N; h++) {
        int m = 128 - __popcll(qs0[h] ^ kk.x) - __popcll(qs1[h] ^ kk.y);
        best = best > m ? best : m;
      }
      match = ((float)best > thresh);
    }
    unsigned long long m = __ballot(match);
    if (m) {
      int base = 0;
      if (lane == 0) base = atomicAdd(&ncand_sh, __popcll(m));
      base = __shfl(base, 0);
      if (match) {
        int pos = base + __popcll(m & ((1ull << lane) - 1ull));
        if (pos < MAXC) idx_sh[nw + pos] = (unsigned short)l;
      }
    }
  }
  __syncthreads();
  int nc = ncand_sh < MAXC ? ncand_sh : MAXC;
  int ntot = nw + nc;
  int ntot_pad = (ntot + 15) & ~15;
  for (int i = ntot + tid; i < ntot_pad; i += 256) idx_sh[i] = 0;
  __syncthreads();

  // ---- Stage 2: fp16 MFMA scoring -> packed fp16 ordered keys in LDS ----
  f16x8 bfrag[4];
  f16x8 bzero = {0, 0, 0, 0, 0, 0, 0, 0};
#pragma unroll
  for (int ks = 0; ks < 4; ks++)
    bfrag[ks] = (col < 4) ? *(const f16x8*)&q_f16[col][ks * 32 + quad * 8] : bzero;

  const unsigned short* kf_h = kf16 + ((size_t)kh << 11) * 128;
  unsigned int creg[NREG];     // 2 fp16 ordered keys per reg
#pragma unroll
  for (int i = 0; i < NREG; i++) creg[i] = 0u;

  for (int cb = 0; cb < 4; cb++) {
    int cbase = cb * CHUNK;
    int chunk_n = ntot_pad - cbase;
    if (chunk_n <= 0) break;
    if (chunk_n > CHUNK) chunk_n = CHUNK;
    int ntiles = chunk_n >> 4;
    for (int t = qh; t < ntiles; t += QH_N) {
      int tb = cbase + t * 16;
      int krow = idx_sh[tb + col];
      const unsigned char* ab =
          (const unsigned char*)(kf_h + (size_t)krow * 128) + quad * 16;
      f16x8 a0 = *(const f16x8*)(ab + 0);
      f16x8 a1 = *(const f16x8*)(ab + 64);
      f16x8 a2 = *(const f16x8*)(ab + 128);
      f16x8 a3 = *(const f16x8*)(ab + 192);
      f32x4 acc = {0.f, 0.f, 0.f, 0.f};
      acc = __builtin_amdgcn_mfma_f32_16x16x32_f16(a0, bfrag[0], acc, 0, 0, 0);
      acc = __builtin_amdgcn_mfma_f32_16x16x32_f16(a1, bfrag[1], acc, 0, 0, 0);
      acc = __builtin_amdgcn_mfma_f32_16x16x32_f16(a2, bfrag[2], acc, 0, 0, 0);
      acc = __builtin_amdgcn_mfma_f32_16x16x32_f16(a3, bfrag[3], acc, 0, 0, 0);
      if (col < 4) {
        unsigned int k01 = pack_okey16(acc[0], acc[1]);
        unsigned int k23 = pack_okey16(acc[2], acc[3]);
        int off = ((tb - cbase) >> 1) + quad * 2;
        buf[col * PLANE32 + off]     = k01;
        buf[col * PLANE32 + off + 1] = k23;
      }
    }
    __syncthreads();
#pragma unroll
    for (int j = 0; j < 4; j++) {
      int m = j * 64 + lane;
      if (2 * m < chunk_n) creg[cb * 4 + j] = buf[qh * PLANE32 + m];
    }
    __syncthreads();
  }
  // reg i covers entries e = i*128 + 2*lane + {0,1}
  const int imax = (ntot + 127) >> 7;

  // per-wave scratch carved from this wave's plane (chunk keys are dead now)
  unsigned int*       histw = &buf[qh * PLANE32];                        // 256 u32
  unsigned long long* selq  = (unsigned long long*)&buf[qh * PLANE32 + 256]; // 208 u64

  // ---- cheap exact max: max over ALL scores == max over included set ----
  unsigned int mx16 = 0;
#pragma unroll
  for (int i = 0; i < NREG; i++) {
    if (i >= imax) break;
    unsigned int u = creg[i];
    int e0 = i * 128 + 2 * lane;
    unsigned int h0 = u & 0xFFFFu, h1 = u >> 16;
    if (e0 < ntot && h0 > mx16) mx16 = h0;
    if (e0 + 1 < ntot && h1 > mx16) mx16 = h1;
  }
#pragma unroll
  for (int off = 32; off > 0; off >>= 1) {
    unsigned int t = __shfl_down(mx16, off);
    mx16 = t > mx16 ? t : mx16;
  }
  mx16 = __shfl(mx16, 0);
  const float mxf = okinv16(mx16);

  // ---- Stage 3: per-wave exact top-k threshold (radix-256, 2 passes) ----
  bool selAll = (nc <= topk);
  unsigned int tkey = 0;
  bool useTie = false;
  int l_cut = S_LEN;
  if (!selAll) {
    unsigned int prefix = 0;
    int want = topk;
    for (int pass = 0; pass < 2; pass++) {
      int sh = 8 - pass * 8;
#pragma unroll
      for (int j = 0; j < 4; j++) histw[lane * 4 + j] = 0;
      lds_fence();
#pragma unroll
      for (int i = 0; i < NREG; i++) {
        if (i >= imax) break;
        unsigned int u = creg[i];
        int e0 = i * 128 + 2 * lane;
#pragma unroll
        for (int h = 0; h < 2; h++) {
          int e = e0 + h;
          if (e >= nw && e < ntot) {
            unsigned int key = h ? (u >> 16) : (u & 0xFFFFu);
            bool match = (pass == 0) || ((key >> 8) == prefix);
            if (match) atomicAdd(&histw[(key >> sh) & 255u], 1u);
          }
        }
      }
      lds_fence();
      unsigned int c0 = histw[lane * 4 + 0];
      unsigned int c1 = histw[lane * 4 + 1];
      unsigned int c2 = histw[lane * 4 + 2];
      unsigned int c3 = histw[lane * 4 + 3];
      unsigned int S3 = c3, S2 = c2 + S3, S1 = c1 + S2, S0 = c0 + S1;
      unsigned int tot = S0;
      unsigned int suf = tot;
#pragma unroll
      for (int off = 1; off < 64; off <<= 1) {
        unsigned int t = __shfl_down(suf, off);
        if (lane + off < 64) suf += t;
      }
      unsigned long long mk = __ballot(suf >= (unsigned int)want);
      int L = 63 - __clzll(mk);
      unsigned int se = suf - tot;
      unsigned int s3 = S3 + se, s2 = S2 + se, s1 = S1 + se, s0 = S0 + se;
      int j; unsigned int above;
      unsigned int w = (unsigned int)want;
      if (s3 >= w)      { j = 3; above = s3 - c3; }
      else if (s2 >= w) { j = 2; above = s2 - c2; }
      else if (s1 >= w) { j = 1; above = s1 - c1; }
      else              { j = 0; above = s0 - c0; }
      int d_me = (lane << 2) | j;
      int wp_me = want - (int)above;
      int digit = __shfl(d_me, L);
      want = __shfl(wp_me, L);
      prefix = (prefix << 8) | (unsigned int)digit;
    }
    tkey = prefix;  // 16-bit ordered key of the 64th-largest candidate
    // exact tie handling (lowest l wins, matching lax.top_k)
    int cgt = 0, ceq = 0;
#pragma unroll
    for (int i = 0; i < NREG; i++) {
      if (i >= imax) break;
      unsigned int u = creg[i];
      int e0 = i * 128 + 2 * lane;
#pragma unroll
      for (int h = 0; h < 2; h++) {
        int e = e0 + h;
        if (e >= nw && e < ntot) {
          unsigned int key = h ? (u >> 16) : (u & 0xFFFFu);
          cgt += (key > tkey);
          ceq += (key == tkey);
        }
      }
    }
#pragma unroll
    for (int off = 32; off > 0; off >>= 1) {
      cgt += __shfl_down(cgt, off);
      ceq += __shfl_down(ceq, off);
    }
    cgt = __shfl(cgt, 0); ceq = __shfl(ceq, 0);
    int rem = topk - cgt;
    if (ceq > rem) {
      useTie = true;
      int lo = 0, hi = S_LEN - 1;
      while (lo < hi) {
        int mid = (lo + hi) >> 1;
        int cn = 0;
#pragma unroll
        for (int i = 0; i < NREG; i++) {
          if (i >= imax) break;
          unsigned int u = creg[i];
          int e0 = i * 128 + 2 * lane;
#pragma unroll
          for (int h = 0; h < 2; h++) {
            int e = e0 + h;
            if (e >= nw && e < ntot) {
              unsigned int key = h ? (u >> 16) : (u & 0xFFFFu);
              cn += (key == tkey && (int)idx_sh[e] <= mid);
            }
          }
        }
#pragma unroll
        for (int off = 32; off > 0; off >>= 1) cn += __shfl_down(cn, off);
        cn = __shfl(cn, 0);
        if (cn >= rem) hi = mid; else lo = mid + 1;
      }
      l_cut = lo;
    }
  }

  // ---- Stage 4: fused select + exp + compact (running register base) ----
  float sum = 0.0f;
  int bse = 0;
#pragma unroll
  for (int i = 0; i < NREG; i++) {
    if (i >= imax) break;
    unsigned int u = creg[i];
    int e0 = i * 128 + 2 * lane;
#pragma unroll
    for (int h = 0; h < 2; h++) {
      int e = e0 + h;
      bool act = false;
      float p = 0.f;
      if (e < ntot) {
        unsigned int key = h ? (u >> 16) : (u & 0xFFFFu);
        bool inc = (e < nw) || selAll;
        if (!inc)
          inc = (key > tkey) ||
                (key == tkey && (!useTie || (int)idx_sh[e] <= l_cut));
        if (inc) { act = true; p = __expf(okinv16(key) - mxf); sum += p; }
      }
      unsigned long long m = __ballot(act);
      if (act) {
        int pi = bse + __popcll(m & ((1ull << lane) - 1ull));
        selq[pi] = ((unsigned long long)idx_sh[e] << 32) |
                   (unsigned long long)__float_as_uint(p);
      }
      bse += (int)__popcll(m);
    }
  }
#pragma unroll
  for (int off = 32; off > 0; off >>= 1) sum += __shfl_down(sum, off);
  sum = __shfl(sum, 0);
  float rinv = 1.0f / sum;

  int nsel = bse;
  int nsel8 = (nsel + 7) & ~7;
  if (lane < nsel8 - nsel) selq[nsel + lane] = 0ull;  // pad: p=0, idx=0
  lds_fence();

  // ---- Stage 5: PV via v_dot2_f32_f16; quarter-wave owns an entry PAIR,
  //      lane owns 8 dims (16B V loads), p packed fp16 ----
  const int sub = lane & 15;        // dims 8*sub .. 8*sub+7
  const int quarter = lane >> 4;
  float av[8] = {0.f, 0.f, 0.f, 0.f, 0.f, 0.f, 0.f, 0.f};
  const uint4* vb4 = (const uint4*)(vf16 + ((size_t)kh << 11) * 64);
  for (int e = 0; e < nsel8; e += 8) {
    ulonglong2 sp = *(const ulonglong2*)&selq[e + 2 * quarter];
    float p0 = __uint_as_float((unsigned int)sp.x);
    float p1 = __uint_as_float((unsigned int)sp.y);
    int l0 = (int)(sp.x >> 32), l1 = (int)(sp.y >> 32);
    f16x2 ph = __builtin_bit_cast(f16x2, pkrtz_u32(p0, p1));
    uint4 v0 = vb4[(size_t)l0 * 16 + sub];
    uint4 v1 = vb4[(size_t)l1 * 16 + sub];
#define DOT2(comp, i0, i1)                                                   \
    {                                                                        \
      unsigned int lo_ = __builtin_amdgcn_perm(v1.comp, v0.comp, 0x05040100u); \
      unsigned int hi_ = __builtin_amdgcn_perm(v1.comp, v0.comp, 0x07060302u); \
      av[i0] = __builtin_amdgcn_fdot2(__builtin_bit_cast(f16x2, lo_), ph,    \
                                      av[i0], false);                        \
      av[i1] = __builtin_amdgcn_fdot2(__builtin_bit_cast(f16x2, hi_), ph,    \
                                      av[i1], false);                        \
    }
    DOT2(x, 0, 1) DOT2(y, 2, 3) DOT2(z, 4, 5) DOT2(w, 6, 7)
#undef DOT2
  }
#pragma unroll
  for (int d = 0; d < 8; d++) {
    av[d] += __shfl_xor(av[d], 16);
    av[d] += __shfl_xor(av[d], 32);
  }
  if (lane < 16) {
    size_t o = (size_t)s * (H_N * D_DIM) + (size_t)(kh * QH_N + qh) * D_DIM
             + (size_t)sub * 8;
    f32x4 r0 = {av[0] * rinv, av[1] * rinv, av[2] * rinv, av[3] * rinv};
    f32x4 r1 = {av[4] * rinv, av[5] * rinv, av[6] * rinv, av[7] * rinv};
    __builtin_nontemporal_store(r0, (f32x4*)(out + o));
    __builtin_nontemporal_store(r1, (f32x4*)(out + o + 4));
  }
}

// ---------------------------------------------------------------------------
extern "C" void kernel_launch(void* const* d_in, const int* in_sizes, int n_in,
                              void* d_out, int out_size, void* d_ws, size_t ws_size,
                              hipStream_t stream) {
  const float* query = (const float*)d_in[0];
  const float* key   = (const float*)d_in[1];
  const float* value = (const float*)d_in[2];
  const float* thr   = (const float*)d_in[3];
  const int* p_topk  = (const int*)d_in[4];
  const int* p_wsz   = (const int*)d_in[5];
  float* out = (float*)d_out;

  // ws: k-signs 8192*16B = 128 KB | kf16 8192*256B = 2 MB | vf16 8192*256B = 2 MB
  char* ws = (char*)d_ws;
  unsigned long long* signs = (unsigned long long*)ws;
  unsigned short* kf16 = (unsigned short*)(ws + (size_t)KH_N * S_LEN * 16);
  unsigned int* vf16 = (unsigned int*)(ws + (size_t)KH_N * S_LEN * 16
                                          + (size_t)KH_N * S_LEN * 256);

  // 16384 k+v rows, 4 rows/wave, 4 waves/block -> 1024 blocks
  pack_kernel<<<1024, 256, 0, stream>>>(key, value, signs, kf16, vf16);

  attn_kernel<<<KH_N * S_LEN, 256, 0, stream>>>(
      query, thr, p_topk, p_wsz, signs, kf16, vf16, out);
}